// Round 1
// baseline (1083.244 us; speedup 1.0000x reference)
//
#include <hip/hip_runtime.h>

// SNN recurrent CUBA-LIF cell, fused dual-GEMM + elementwise dynamics.
// current = CDECAY*pre_I + X@Wp + bp + S@Wr + br, masked; volt/spike/vth elementwise.
// fp32 vector GEMM (no fp32 MFMA on CDNA4); correctness-first baseline.

#define CDECAY   0.5f
#define VDECAY   0.75f
#define TH_AMP   0.05f
#define TH_DECAY 0.9f
#define BASE_TH  1.0f

#define BM 64
#define BN 64
#define BK 16
#define TM 4
#define TN 4
// LDS row padding: keeps float4 alignment (stride 68*4B, 16B-multiple) and
// breaks power-of-2 bank aliasing.
#define PAD 4

__global__ __launch_bounds__(256)
void snn_dualgemm_fp32(const float* __restrict__ X,     // M x K  input_data
                       const float* __restrict__ S,     // M x K  pre_spike (K==N==HID)
                       const float* __restrict__ preI,  // M x N
                       const float* __restrict__ preV,  // M x N
                       const float* __restrict__ preTh, // M x N
                       const float* __restrict__ mask,  // M x N
                       const float* __restrict__ Wp,    // K x N
                       const float* __restrict__ bp,    // N
                       const float* __restrict__ Wr,    // K x N
                       const float* __restrict__ br,    // N
                       float* __restrict__ o_spk,
                       float* __restrict__ o_spk2,
                       float* __restrict__ o_cur,
                       float* __restrict__ o_volt,
                       float* __restrict__ o_vth,
                       int M, int N, int K)
{
    __shared__ float Xs [BK][BM + PAD];  // stored transposed: [k][m]
    __shared__ float Ss [BK][BM + PAD];
    __shared__ float Wps[BK][BN + PAD];  // natural: [k][n]
    __shared__ float Wrs[BK][BN + PAD];

    const int tid = threadIdx.x;          // 0..255
    const int tx  = tid & 15;             // 0..15 -> n micro-tile
    const int ty  = tid >> 4;             // 0..15 -> m micro-tile
    const int bm  = blockIdx.y * BM;
    const int bn  = blockIdx.x * BN;

    // A-tile loads: 64x16 floats, one float4 per thread
    const int arow = tid >> 2;            // 0..63
    const int acol = (tid & 3) << 2;      // 0,4,8,12
    // B-tile loads: 16x64 floats, one float4 per thread
    const int brow = tid >> 4;            // 0..15
    const int bcol = (tid & 15) << 2;     // 0..60

    float acc[TM][TN] = {};

    for (int k0 = 0; k0 < K; k0 += BK) {
        const float4 xa = *(const float4*)&X [(size_t)(bm + arow) * K + (k0 + acol)];
        const float4 sa = *(const float4*)&S [(size_t)(bm + arow) * K + (k0 + acol)];
        const float4 wp = *(const float4*)&Wp[(size_t)(k0 + brow) * N + (bn + bcol)];
        const float4 wr = *(const float4*)&Wr[(size_t)(k0 + brow) * N + (bn + bcol)];

        __syncthreads();   // previous iteration's LDS reads complete
        Xs[acol + 0][arow] = xa.x;  Xs[acol + 1][arow] = xa.y;
        Xs[acol + 2][arow] = xa.z;  Xs[acol + 3][arow] = xa.w;
        Ss[acol + 0][arow] = sa.x;  Ss[acol + 1][arow] = sa.y;
        Ss[acol + 2][arow] = sa.z;  Ss[acol + 3][arow] = sa.w;
        *(float4*)&Wps[brow][bcol] = wp;
        *(float4*)&Wrs[brow][bcol] = wr;
        __syncthreads();

#pragma unroll
        for (int k = 0; k < BK; ++k) {
            const float4 a1 = *(const float4*)&Xs [k][ty * TM];
            const float4 a2 = *(const float4*)&Ss [k][ty * TM];
            const float4 b1 = *(const float4*)&Wps[k][tx * TN];
            const float4 b2 = *(const float4*)&Wrs[k][tx * TN];
            const float a1v[TM] = {a1.x, a1.y, a1.z, a1.w};
            const float a2v[TM] = {a2.x, a2.y, a2.z, a2.w};
            const float b1v[TN] = {b1.x, b1.y, b1.z, b1.w};
            const float b2v[TN] = {b2.x, b2.y, b2.z, b2.w};
#pragma unroll
            for (int i = 0; i < TM; ++i)
#pragma unroll
                for (int j = 0; j < TN; ++j)
                    acc[i][j] = fmaf(a1v[i], b1v[j],
                                 fmaf(a2v[i], b2v[j], acc[i][j]));
        }
    }

    // ---- fused LIF epilogue ----
    const int n0 = bn + tx * TN;
    const float4 bp4 = *(const float4*)&bp[n0];
    const float4 br4 = *(const float4*)&br[n0];

#pragma unroll
    for (int i = 0; i < TM; ++i) {
        const int m = bm + ty * TM + i;
        const size_t base = (size_t)m * N + n0;
        const float4 pI = *(const float4*)&preI [base];
        const float4 pV = *(const float4*)&preV [base];
        const float4 pT = *(const float4*)&preTh[base];
        const float4 mk = *(const float4*)&mask [base];
        const float4 sp = *(const float4*)&S    [base];  // pre_spike, M x HID (HID==N)

        float4 cur, vo, ou, vt;
        {
            const float pIv[4] = {pI.x, pI.y, pI.z, pI.w};
            const float pVv[4] = {pV.x, pV.y, pV.z, pV.w};
            const float pTv[4] = {pT.x, pT.y, pT.z, pT.w};
            const float mkv[4] = {mk.x, mk.y, mk.z, mk.w};
            const float spv[4] = {sp.x, sp.y, sp.z, sp.w};
            const float bpv[4] = {bp4.x, bp4.y, bp4.z, bp4.w};
            const float brv[4] = {br4.x, br4.y, br4.z, br4.w};
            float curv[4], vov[4], ouv[4], vtv[4];
#pragma unroll
            for (int j = 0; j < TN; ++j) {
                float c = CDECAY * pIv[j] + acc[i][j] + bpv[j] + brv[j];
                c *= mkv[j];
                float v = VDECAY * pVv[j] * (1.0f - spv[j]) + c;
                float o = (v > pTv[j]) ? 1.0f : 0.0f;
                float t = (o != 0.0f) ? (pTv[j] + TH_AMP)
                                      : fmaxf(pTv[j] * TH_DECAY, BASE_TH);
                curv[j] = c; vov[j] = v; ouv[j] = o; vtv[j] = t;
            }
            cur = make_float4(curv[0], curv[1], curv[2], curv[3]);
            vo  = make_float4(vov[0],  vov[1],  vov[2],  vov[3]);
            ou  = make_float4(ouv[0],  ouv[1],  ouv[2],  ouv[3]);
            vt  = make_float4(vtv[0],  vtv[1],  vtv[2],  vtv[3]);
        }
        *(float4*)&o_spk [base] = ou;
        *(float4*)&o_spk2[base] = ou;
        *(float4*)&o_cur [base] = cur;
        *(float4*)&o_volt[base] = vo;
        *(float4*)&o_vth [base] = vt;
    }
}

extern "C" void kernel_launch(void* const* d_in, const int* in_sizes, int n_in,
                              void* d_out, int out_size, void* d_ws, size_t ws_size,
                              hipStream_t stream) {
    const float* X    = (const float*)d_in[0];   // input_data  (B, IN_DIM)
    const float* S    = (const float*)d_in[1];   // pre_spike   (B, HID)
    const float* preI = (const float*)d_in[2];   // pre_current (B, HID)
    const float* preV = (const float*)d_in[3];   // pre_volt    (B, HID)
    const float* preT = (const float*)d_in[4];   // pre_vth     (B, HID)
    const float* mask = (const float*)d_in[5];   // mask        (B, HID)
    const float* Wp   = (const float*)d_in[6];   // W_psp (IN_DIM, HID)
    const float* bp   = (const float*)d_in[7];   // b_psp (HID,)
    const float* Wr   = (const float*)d_in[8];   // W_rec (HID, HID)
    const float* br   = (const float*)d_in[9];   // b_rec (HID,)

    const int HID = in_sizes[7];
    const int B   = in_sizes[1] / HID;
    const int K   = in_sizes[0] / B;             // IN_DIM; == HID here (shared K-loop)

    const size_t n = (size_t)B * HID;
    const int nchunk = (int)(out_size / n);      // pytree: (out, (out, cur, volt, vth)) -> 5
    float* o = (float*)d_out;
    float* o_spk  = o;
    float* o_spk2 = (nchunk >= 5) ? o + n : o;
    float* o_cur  = o + (size_t)((nchunk >= 5) ? 2 : 1) * n;
    float* o_volt = o + (size_t)((nchunk >= 5) ? 3 : 2) * n;
    float* o_vth  = o + (size_t)((nchunk >= 5) ? 4 : 3) * n;

    dim3 grid(HID / BN, B / BM);
    snn_dualgemm_fp32<<<grid, 256, 0, stream>>>(
        X, S, preI, preV, preT, mask, Wp, bp, Wr, br,
        o_spk, o_spk2, o_cur, o_volt, o_vth, B, HID, K);
}